// Round 1
// baseline (373.583 us; speedup 1.0000x reference)
//
#include <hip/hip_runtime.h>
#include <hip/hip_bf16.h>
#include <stdint.h>

typedef __bf16 bf16_t;
typedef __bf16 bf16x8 __attribute__((ext_vector_type(8)));
typedef float  f32x4  __attribute__((ext_vector_type(4)));

#define D_MODEL 1024
#define NHEAD   16
#define DEPTH   64
#define BATCH   4
#define SEQ     2048
#define MROWS   (BATCH*SEQ)

__device__ __forceinline__ void gload16(const void* g, void* l) {
    __builtin_amdgcn_global_load_lds(
        (__attribute__((address_space(1))) void*)(uintptr_t)g,
        (__attribute__((address_space(3))) void*)l,
        16, 0, 0);
}

// ---------------- f32 -> bf16 convert (16B/lane) ----------------
__global__ __launch_bounds__(256) void cvt_kernel(const float* __restrict__ src,
                                                  bf16_t* __restrict__ dst, int n8) {
    int i = blockIdx.x * 256 + threadIdx.x;
    if (i >= n8) return;
    const float4* s4 = (const float4*)src;
    float4 a = s4[2*(size_t)i], b = s4[2*(size_t)i + 1];
    bf16x8 o;
    o[0] = (bf16_t)a.x; o[1] = (bf16_t)a.y; o[2] = (bf16_t)a.z; o[3] = (bf16_t)a.w;
    o[4] = (bf16_t)b.x; o[5] = (bf16_t)b.y; o[6] = (bf16_t)b.z; o[7] = (bf16_t)b.w;
    *(bf16x8*)(dst + 8*(size_t)i) = o;
}

// ---------------- GEMM: C[M,N] = A[M,K] * Bw[N,K]^T + bias ----------------
// 128x128 tile, BK=64, 4 waves (2x2 of 64x64), mfma 16x16x32 bf16.
// LDS staged via global_load_lds(16B) with XOR-swizzled *source* (linear dest),
// reads apply the same XOR -> ~2-way instead of 16-way bank conflict.
template<int OUT_BF16>
__global__ __launch_bounds__(256) void gemm_bt(const bf16_t* __restrict__ A,
                                               const bf16_t* __restrict__ Bw,
                                               const float* __restrict__ bias,
                                               bf16_t* __restrict__ Cb,
                                               float* __restrict__ Cf,
                                               int M, int N, int K) {
    __shared__ bf16_t As[128*64];
    __shared__ bf16_t Bs[128*64];
    const int tid  = threadIdx.x;
    const int wave = tid >> 6, lane = tid & 63;
    const int lr = lane & 15, lk = (lane >> 4) * 8;
    const int bm = blockIdx.x * 128, bn = blockIdx.y * 128;
    const int wr = (wave >> 1) * 64, wc = (wave & 1) * 64;

    f32x4 acc[4][4] = {};

    for (int kt = 0; kt < K; kt += 64) {
#pragma unroll
        for (int p = 0; p < 4; ++p) {
            int chunk = p*256 + tid;          // 0..1023 (16B chunks)
            int r  = chunk >> 3;              // tile row 0..127
            int cs = ((chunk & 7) ^ (r & 7)) * 8;  // pre-swizzled source col
            gload16(A  + (size_t)(bm + r)*K + kt + cs, As + (size_t)(p*256 + wave*64)*8);
            gload16(Bw + (size_t)(bn + r)*K + kt + cs, Bs + (size_t)(p*256 + wave*64)*8);
        }
        __syncthreads();
        const char* AsB = (const char*)As;
        const char* BsB = (const char*)Bs;
#pragma unroll
        for (int ks = 0; ks < 2; ++ks) {
            int kb = (ks*32 + lk) * 2;
            bf16x8 af[4], bfv[4];
#pragma unroll
            for (int mi = 0; mi < 4; ++mi) {
                int row = wr + mi*16 + lr;
                af[mi] = *(const bf16x8*)(AsB + ((row*128 + kb) ^ ((row & 7) << 4)));
            }
#pragma unroll
            for (int ni = 0; ni < 4; ++ni) {
                int row = wc + ni*16 + lr;
                bfv[ni] = *(const bf16x8*)(BsB + ((row*128 + kb) ^ ((row & 7) << 4)));
            }
#pragma unroll
            for (int mi = 0; mi < 4; ++mi)
#pragma unroll
                for (int ni = 0; ni < 4; ++ni)
                    acc[mi][ni] = __builtin_amdgcn_mfma_f32_16x16x32_bf16(
                        af[mi], bfv[ni], acc[mi][ni], 0, 0, 0);
        }
        __syncthreads();
    }

#pragma unroll
    for (int ni = 0; ni < 4; ++ni) {
        int col = bn + wc + ni*16 + lr;
        float bv = bias[col];
#pragma unroll
        for (int mi = 0; mi < 4; ++mi) {
#pragma unroll
            for (int j = 0; j < 4; ++j) {
                int row = bm + wr + mi*16 + (lane >> 4)*4 + j;
                float vv = acc[mi][ni][j] + bv;
                if (OUT_BF16) Cb[(size_t)row*N + col] = (bf16_t)vv;
                else          Cf[(size_t)row*N + col] = vv;
            }
        }
    }
}

// ---------------- Flash attention ----------------
// Q/K/V projected, stored [B*S][1024] bf16 (head h = cols h*64..h*64+63).
// Block: 128 q-rows, 4 waves (32 rows each); 64-key tiles; online softmax.
__global__ __launch_bounds__(256) void attn_kernel(const bf16_t* __restrict__ Qp,
                                                   const bf16_t* __restrict__ Kp,
                                                   const bf16_t* __restrict__ Vp,
                                                   const int* __restrict__ mask,
                                                   bf16_t* __restrict__ AO) {
    __shared__ bf16_t Ks[64*64];   // [key][d], XOR-swizzled
    __shared__ bf16_t Vt[64*64];   // [d][key], XOR-swizzled (transposed at stage)
    __shared__ bf16_t Ps[128*64];  // [qrow][key], XOR-swizzled
    __shared__ float  mkf[64];

    const int tid  = threadIdx.x;
    const int wave = tid >> 6, lane = tid & 63;
    const int lr = lane & 15, lg = lane >> 4;
    const int lk = lg * 8;
    const int b = blockIdx.z, h = blockIdx.y, q0 = blockIdx.x * 128;

    const size_t base = (size_t)b * SEQ * D_MODEL + (size_t)h * DEPTH;

    // Q fragments in registers for the whole K-loop
    bf16x8 qf[2][2];
#pragma unroll
    for (int mi = 0; mi < 2; ++mi)
#pragma unroll
        for (int kk = 0; kk < 2; ++kk)
            qf[mi][kk] = *(const bf16x8*)&Qp[base + (size_t)(q0 + wave*32 + mi*16 + lr)*D_MODEL + kk*32 + lk];

    f32x4 o[2][4] = {};
    float m_run[2][4], l_run[2][4];
#pragma unroll
    for (int mi = 0; mi < 2; ++mi)
#pragma unroll
        for (int j = 0; j < 4; ++j) { m_run[mi][j] = -1e9f; l_run[mi][j] = 0.f; }

    char* KsB = (char*)Ks;
    char* VtB = (char*)Vt;
    char* PsB = (char*)Ps;

    for (int kt = 0; kt < SEQ; kt += 64) {
        // stage K tile via global_load_lds (pre-swizzled source, linear dest)
#pragma unroll
        for (int p = 0; p < 2; ++p) {
            int chunk = p*256 + tid;          // 0..511
            int r  = chunk >> 3;              // key 0..63
            int cs = ((chunk & 7) ^ (r & 7)) * 8;
            gload16(Kp + base + (size_t)(kt + r)*D_MODEL + cs, Ks + (size_t)(p*256 + wave*64)*8);
        }
        if (tid < 64) mkf[tid] = (mask[b*SEQ + kt + tid] == 0) ? 1.f : 0.f;
        // stage V transposed (register path, swizzled scatter)
#pragma unroll
        for (int p = 0; p < 2; ++p) {
            int t = p*256 + tid;              // 0..511
            int key = t & 63, d0 = (t >> 6) * 8;
            bf16x8 vv = *(const bf16x8*)&Vp[base + (size_t)(kt + key)*D_MODEL + d0];
#pragma unroll
            for (int e = 0; e < 8; ++e) {
                int d = d0 + e;
                int byt = (d*128 + key*2) ^ ((d & 7) << 4);
                *(bf16_t*)(VtB + byt) = vv[e];
            }
        }
        __syncthreads();

        // S = Q K^T   (C-layout: col=key=lr+16*nj, row=qrow=lg*4+j+16*mi)
        f32x4 s[2][4] = {};
#pragma unroll
        for (int kk = 0; kk < 2; ++kk) {
            int kb = (kk*32 + lk) * 2;
            bf16x8 kf[4];
#pragma unroll
            for (int nj = 0; nj < 4; ++nj) {
                int key = nj*16 + lr;
                kf[nj] = *(const bf16x8*)(KsB + ((key*128 + kb) ^ ((key & 7) << 4)));
            }
#pragma unroll
            for (int mi = 0; mi < 2; ++mi)
#pragma unroll
                for (int nj = 0; nj < 4; ++nj)
                    s[mi][nj] = __builtin_amdgcn_mfma_f32_16x16x32_bf16(
                        qf[mi][kk], kf[nj], s[mi][nj], 0, 0, 0);
        }

        float mflag[4];
#pragma unroll
        for (int nj = 0; nj < 4; ++nj) mflag[nj] = mkf[nj*16 + lr];

        // mask + scale + online softmax (16-lane shfl reduce per row group)
#pragma unroll
        for (int mi = 0; mi < 2; ++mi) {
#pragma unroll
            for (int nj = 0; nj < 4; ++nj)
#pragma unroll
                for (int j = 0; j < 4; ++j)
                    s[mi][nj][j] = (mflag[nj] != 0.f) ? -1e9f : s[mi][nj][j] * 0.125f;
#pragma unroll
            for (int j = 0; j < 4; ++j) {
                float rm = fmaxf(fmaxf(s[mi][0][j], s[mi][1][j]),
                                 fmaxf(s[mi][2][j], s[mi][3][j]));
                rm = fmaxf(rm, __shfl_xor(rm, 1));
                rm = fmaxf(rm, __shfl_xor(rm, 2));
                rm = fmaxf(rm, __shfl_xor(rm, 4));
                rm = fmaxf(rm, __shfl_xor(rm, 8));
                float mo = m_run[mi][j];
                float mn = fmaxf(mo, rm);
                float fac = __expf(mo - mn);
                m_run[mi][j] = mn;
                float rs = 0.f;
#pragma unroll
                for (int nj = 0; nj < 4; ++nj) {
                    float pv = __expf(s[mi][nj][j] - mn);
                    s[mi][nj][j] = pv;
                    rs += pv;
                }
                rs += __shfl_xor(rs, 1);
                rs += __shfl_xor(rs, 2);
                rs += __shfl_xor(rs, 4);
                rs += __shfl_xor(rs, 8);
                l_run[mi][j] = l_run[mi][j]*fac + rs;
#pragma unroll
                for (int dj = 0; dj < 4; ++dj) o[mi][dj][j] *= fac;
            }
        }

        // P -> LDS (bf16, swizzled)
#pragma unroll
        for (int mi = 0; mi < 2; ++mi)
#pragma unroll
            for (int nj = 0; nj < 4; ++nj) {
                int key = nj*16 + lr;
#pragma unroll
                for (int j = 0; j < 4; ++j) {
                    int qr = wave*32 + mi*16 + lg*4 + j;
                    int byt = (qr*128 + key*2) ^ ((qr & 7) << 4);
                    *(bf16_t*)(PsB + byt) = (bf16_t)s[mi][nj][j];
                }
            }
        __syncthreads();

        // O += P * V
#pragma unroll
        for (int kk = 0; kk < 2; ++kk) {
            int kb = (kk*32 + lk) * 2;
            bf16x8 pf[2], vf[4];
#pragma unroll
            for (int mi = 0; mi < 2; ++mi) {
                int qr = wave*32 + mi*16 + lr;
                pf[mi] = *(const bf16x8*)(PsB + ((qr*128 + kb) ^ ((qr & 7) << 4)));
            }
#pragma unroll
            for (int dj = 0; dj < 4; ++dj) {
                int d = dj*16 + lr;
                vf[dj] = *(const bf16x8*)(VtB + ((d*128 + kb) ^ ((d & 7) << 4)));
            }
#pragma unroll
            for (int mi = 0; mi < 2; ++mi)
#pragma unroll
                for (int dj = 0; dj < 4; ++dj)
                    o[mi][dj] = __builtin_amdgcn_mfma_f32_16x16x32_bf16(
                        pf[mi], vf[dj], o[mi][dj], 0, 0, 0);
        }
        __syncthreads();
    }

    // epilogue: O/l, write [b][s][h*64+d] bf16
#pragma unroll
    for (int mi = 0; mi < 2; ++mi)
#pragma unroll
        for (int j = 0; j < 4; ++j) {
            float inv = 1.f / l_run[mi][j];
            int row = q0 + wave*32 + mi*16 + lg*4 + j;
#pragma unroll
            for (int dj = 0; dj < 4; ++dj)
                AO[base + (size_t)row*D_MODEL + dj*16 + lr] = (bf16_t)(o[mi][dj][j] * inv);
        }
}

extern "C" void kernel_launch(void* const* d_in, const int* in_sizes, int n_in,
                              void* d_out, int out_size, void* d_ws, size_t ws_size,
                              hipStream_t stream) {
    (void)in_sizes; (void)n_in; (void)out_size; (void)ws_size;
    const float* q    = (const float*)d_in[0];
    const float* k    = (const float*)d_in[1];
    const float* v    = (const float*)d_in[2];
    const int*   mask = (const int*)d_in[3];
    const float* wq_w = (const float*)d_in[4];
    const float* wq_b = (const float*)d_in[5];
    const float* wk_w = (const float*)d_in[6];
    const float* wk_b = (const float*)d_in[7];
    const float* wv_w = (const float*)d_in[8];
    const float* wv_b = (const float*)d_in[9];
    const float* wo_w = (const float*)d_in[10];
    const float* wo_b = (const float*)d_in[11];
    float* out = (float*)d_out;

    const size_t ACT = (size_t)MROWS * D_MODEL;   // 8.4M elems
    const size_t WSZ = (size_t)D_MODEL * D_MODEL; // 1M elems
    bf16_t* Xb = (bf16_t*)d_ws;   // reused: q/k/v bf16 input, then attn output
    bf16_t* Qp = Xb + ACT;
    bf16_t* Kp = Qp + ACT;
    bf16_t* Vp = Kp + ACT;
    bf16_t* Wq = Vp + ACT;
    bf16_t* Wk = Wq + WSZ;
    bf16_t* Wv = Wk + WSZ;
    bf16_t* Wo = Wv + WSZ;
    bf16_t* AO = Xb;
    // total workspace: 4*16.78MB + 4*2.10MB = 75.5 MB

    const int wn8 = (int)(WSZ/8), an8 = (int)(ACT/8);
    cvt_kernel<<<dim3(wn8/256), dim3(256), 0, stream>>>(wq_w, Wq, wn8);
    cvt_kernel<<<dim3(wn8/256), dim3(256), 0, stream>>>(wk_w, Wk, wn8);
    cvt_kernel<<<dim3(wn8/256), dim3(256), 0, stream>>>(wv_w, Wv, wn8);
    cvt_kernel<<<dim3(wn8/256), dim3(256), 0, stream>>>(wo_w, Wo, wn8);

    dim3 ggrid(MROWS/128, D_MODEL/128);
    cvt_kernel<<<dim3(an8/256), dim3(256), 0, stream>>>(q, Xb, an8);
    gemm_bt<1><<<ggrid, dim3(256), 0, stream>>>(Xb, Wq, wq_b, Qp, nullptr, MROWS, D_MODEL, D_MODEL);
    cvt_kernel<<<dim3(an8/256), dim3(256), 0, stream>>>(k, Xb, an8);
    gemm_bt<1><<<ggrid, dim3(256), 0, stream>>>(Xb, Wk, wk_b, Kp, nullptr, MROWS, D_MODEL, D_MODEL);
    cvt_kernel<<<dim3(an8/256), dim3(256), 0, stream>>>(v, Xb, an8);
    gemm_bt<1><<<ggrid, dim3(256), 0, stream>>>(Xb, Wv, wv_b, Vp, nullptr, MROWS, D_MODEL, D_MODEL);

    attn_kernel<<<dim3(SEQ/128, NHEAD, BATCH), dim3(256), 0, stream>>>(Qp, Kp, Vp, mask, AO);

    gemm_bt<0><<<ggrid, dim3(256), 0, stream>>>(AO, Wo, wo_b, nullptr, out, MROWS, D_MODEL, D_MODEL);
}

// Round 2
// 298.002 us; speedup vs baseline: 1.2536x; 1.2536x over previous
//
#include <hip/hip_runtime.h>
#include <hip/hip_bf16.h>
#include <stdint.h>

typedef __bf16 bf16_t;
typedef __bf16 bf16x8 __attribute__((ext_vector_type(8)));
typedef __bf16 bf16x2 __attribute__((ext_vector_type(2)));
typedef float  f32x4  __attribute__((ext_vector_type(4)));
typedef float  f32x16 __attribute__((ext_vector_type(16)));
typedef unsigned int u32;
typedef u32 u32x4 __attribute__((ext_vector_type(4)));

#define D_MODEL 1024
#define NHEAD   16
#define DEPTH   64
#define BATCH   4
#define SEQ     2048
#define MROWS   (BATCH*SEQ)

// 0.125 (1/sqrt(64)) * log2(e): softmax done in exp2 domain
#define SC 0.18033688011112042f

__device__ __forceinline__ void gload16(const void* g, void* l) {
    __builtin_amdgcn_global_load_lds(
        (__attribute__((address_space(1))) void*)(uintptr_t)g,
        (__attribute__((address_space(3))) void*)l,
        16, 0, 0);
}

__device__ __forceinline__ u32 pk2(float a, float b) {
    bf16x2 t; t[0] = (bf16_t)a; t[1] = (bf16_t)b;
    return __builtin_bit_cast(u32, t);
}

// ---------------- f32 -> bf16 convert (16B/lane) ----------------
__global__ __launch_bounds__(256) void cvt_kernel(const float* __restrict__ src,
                                                  bf16_t* __restrict__ dst, int n8) {
    int i = blockIdx.x * 256 + threadIdx.x;
    if (i >= n8) return;
    const float4* s4 = (const float4*)src;
    float4 a = s4[2*(size_t)i], b = s4[2*(size_t)i + 1];
    bf16x8 o;
    o[0] = (bf16_t)a.x; o[1] = (bf16_t)a.y; o[2] = (bf16_t)a.z; o[3] = (bf16_t)a.w;
    o[4] = (bf16_t)b.x; o[5] = (bf16_t)b.y; o[6] = (bf16_t)b.z; o[7] = (bf16_t)b.w;
    *(bf16x8*)(dst + 8*(size_t)i) = o;
}

// ---------------- GEMM: C[M,N] = A[M,K] * Bw[N,K]^T + bias ----------------
template<int OUT_BF16>
__global__ __launch_bounds__(256) void gemm_bt(const bf16_t* __restrict__ A,
                                               const bf16_t* __restrict__ Bw,
                                               const float* __restrict__ bias,
                                               bf16_t* __restrict__ Cb,
                                               float* __restrict__ Cf,
                                               int M, int N, int K) {
    __shared__ bf16_t As[128*64];
    __shared__ bf16_t Bs[128*64];
    const int tid  = threadIdx.x;
    const int wave = tid >> 6, lane = tid & 63;
    const int lr = lane & 15, lk = (lane >> 4) * 8;
    const int bm = blockIdx.x * 128, bn = blockIdx.y * 128;
    const int wr = (wave >> 1) * 64, wc = (wave & 1) * 64;

    f32x4 acc[4][4] = {};

    for (int kt = 0; kt < K; kt += 64) {
#pragma unroll
        for (int p = 0; p < 4; ++p) {
            int chunk = p*256 + tid;
            int r  = chunk >> 3;
            int cs = ((chunk & 7) ^ (r & 7)) * 8;
            gload16(A  + (size_t)(bm + r)*K + kt + cs, As + (size_t)(p*256 + wave*64)*8);
            gload16(Bw + (size_t)(bn + r)*K + kt + cs, Bs + (size_t)(p*256 + wave*64)*8);
        }
        __syncthreads();
        const char* AsB = (const char*)As;
        const char* BsB = (const char*)Bs;
#pragma unroll
        for (int ks = 0; ks < 2; ++ks) {
            int kb = (ks*32 + lk) * 2;
            bf16x8 af[4], bfv[4];
#pragma unroll
            for (int mi = 0; mi < 4; ++mi) {
                int row = wr + mi*16 + lr;
                af[mi] = *(const bf16x8*)(AsB + ((row*128 + kb) ^ ((row & 7) << 4)));
            }
#pragma unroll
            for (int ni = 0; ni < 4; ++ni) {
                int row = wc + ni*16 + lr;
                bfv[ni] = *(const bf16x8*)(BsB + ((row*128 + kb) ^ ((row & 7) << 4)));
            }
#pragma unroll
            for (int mi = 0; mi < 4; ++mi)
#pragma unroll
                for (int ni = 0; ni < 4; ++ni)
                    acc[mi][ni] = __builtin_amdgcn_mfma_f32_16x16x32_bf16(
                        af[mi], bfv[ni], acc[mi][ni], 0, 0, 0);
        }
        __syncthreads();
    }

#pragma unroll
    for (int ni = 0; ni < 4; ++ni) {
        int col = bn + wc + ni*16 + lr;
        float bv = bias[col];
#pragma unroll
        for (int mi = 0; mi < 4; ++mi) {
#pragma unroll
            for (int j = 0; j < 4; ++j) {
                int row = bm + wr + mi*16 + (lane >> 4)*4 + j;
                float vv = acc[mi][ni][j] + bv;
                if (OUT_BF16) Cb[(size_t)row*N + col] = (bf16_t)vv;
                else          Cf[(size_t)row*N + col] = vv;
            }
        }
    }
}

// ---------------- Flash attention, swapped-QK in-register softmax ----------------
// Per block: 128 q-rows, 4 waves x 32 q each. 64-key tiles, double-buffered LDS,
// one barrier per tile. S^T = mfma(K, Q^T) so each lane owns one q-row (col=lane&31);
// softmax is in-lane tree + one shfl_xor(32). P packed to bf16 in-register and fed
// to PV (O^T = mfma(V^T, P^T)) via 8 half-wave shuffles per tile. Defer-max (THR=8).
__global__ __launch_bounds__(256) void attn_kernel(const bf16_t* __restrict__ Qp,
                                                   const bf16_t* __restrict__ Kp,
                                                   const bf16_t* __restrict__ Vp,
                                                   const int* __restrict__ mask,
                                                   bf16_t* __restrict__ AO) {
    __shared__ bf16_t Ks[2][64*64];   // [key][d], XOR-swizzled, double-buffered
    __shared__ bf16_t Vt[2][64*64];   // [d][key], XOR-swizzled (transposed at stage)
    __shared__ float  mb[2][64];      // additive mask bias (0 or -1e30)

    const int tid  = threadIdx.x;
    const int wave = tid >> 6, lane = tid & 63;
    const int lr5 = lane & 31;
    const int hi  = lane >> 5;
    const bool hib = (hi != 0);
    const int b = blockIdx.z, h = blockIdx.y, q0 = blockIdx.x * 128;
    const int qw = q0 + wave*32;
    const size_t base = (size_t)b * SEQ * D_MODEL + (size_t)h * DEPTH;

    // Q fragments (B-operand: lane holds Q[q = qw+lr5][d = dc*16 + hi*8 + e])
    bf16x8 qf[4];
#pragma unroll
    for (int dc = 0; dc < 4; ++dc)
        qf[dc] = *(const bf16x8*)&Qp[base + (size_t)(qw + lr5)*D_MODEL + dc*16 + hi*8];

    f32x16 o0 = {}, o1 = {};         // O^T accumulators: d-tiles 0..31 / 32..63, col=q
    float m_run = -1e30f, l_run = 0.f;

    const int vkey = tid & 63, vd = (tid >> 6) * 8;

    // ---- prologue: stage tile 0 into buffer 0
    {
#pragma unroll
        for (int p = 0; p < 2; ++p) {
            int chunk = p*256 + tid; int r = chunk >> 3;
            int cs = ((chunk & 7) ^ (r & 7)) * 8;
            gload16(Kp + base + (size_t)r*D_MODEL + cs, (bf16_t*)Ks[0] + (size_t)chunk*8);
        }
        if (tid < 64) mb[0][tid] = (mask[(size_t)b*SEQ + tid] == 0) ? -1e30f : 0.f;
        bf16x8 vv0[2];
#pragma unroll
        for (int p = 0; p < 2; ++p)
            vv0[p] = *(const bf16x8*)&Vp[base + (size_t)vkey*D_MODEL + vd + p*32];
        char* VtB = (char*)Vt[0];
#pragma unroll
        for (int p = 0; p < 2; ++p)
#pragma unroll
            for (int e = 0; e < 8; ++e) {
                int d = vd + p*32 + e;
                *(bf16_t*)(VtB + ((d*128 + vkey*2) ^ ((d & 7) << 4))) = vv0[p][e];
            }
    }
    __syncthreads();

    for (int t = 0; t < SEQ/64; ++t) {
        const int cur = t & 1, nxt = cur ^ 1;
        bf16x8 vvn[2];
        const bool has_next = (t + 1 < SEQ/64);
        if (has_next) {
#pragma unroll
            for (int p = 0; p < 2; ++p) {
                int chunk = p*256 + tid; int r = chunk >> 3;
                int cs = ((chunk & 7) ^ (r & 7)) * 8;
                gload16(Kp + base + (size_t)((t+1)*64 + r)*D_MODEL + cs,
                        (bf16_t*)Ks[nxt] + (size_t)chunk*8);
            }
#pragma unroll
            for (int p = 0; p < 2; ++p)
                vvn[p] = *(const bf16x8*)&Vp[base + (size_t)((t+1)*64 + vkey)*D_MODEL + vd + p*32];
            if (tid < 64) mb[nxt][tid] = (mask[(size_t)b*SEQ + (t+1)*64 + tid] == 0) ? -1e30f : 0.f;
        }

        // ---- QK^T: S^T[key][q], key-subtiles kt=0 (s0) / kt=1 (s1)
        const char* KsB = (const char*)Ks[cur];
        f32x16 s0 = {}, s1 = {};
#pragma unroll
        for (int dc = 0; dc < 4; ++dc) {
            int colb = dc*32 + hi*16;
            {
                int row = lr5;
                bf16x8 kf = *(const bf16x8*)(KsB + ((row*128 + colb) ^ ((row & 7) << 4)));
                s0 = __builtin_amdgcn_mfma_f32_32x32x16_bf16(kf, qf[dc], s0, 0, 0, 0);
            }
            {
                int row = 32 + lr5;
                bf16x8 kf = *(const bf16x8*)(KsB + ((row*128 + colb) ^ ((row & 7) << 4)));
                s1 = __builtin_amdgcn_mfma_f32_32x32x16_bf16(kf, qf[dc], s1, 0, 0, 0);
            }
        }

        // ---- mask bias (broadcast reads; key-local = (r&3) + 8*(r>>2) + 4*hi)
        const float* mbp = mb[cur];
        f32x4 mv[2][4];
#pragma unroll
        for (int kt = 0; kt < 2; ++kt)
#pragma unroll
            for (int g = 0; g < 4; ++g)
                mv[kt][g] = *(const f32x4*)&mbp[kt*32 + g*8 + hi*4];

        float pv[32];
#pragma unroll
        for (int r = 0; r < 16; ++r) {
            pv[r]      = s0[r]*SC + mv[0][r>>2][r&3];
            pv[16 + r] = s1[r]*SC + mv[1][r>>2][r&3];
        }

        // ---- online softmax (exp2 domain), full row = own 32 + partner 32
        float rmax = pv[0];
#pragma unroll
        for (int r = 1; r < 32; ++r) rmax = fmaxf(rmax, pv[r]);
        rmax = fmaxf(rmax, __shfl_xor(rmax, 32));

        if (!__all(rmax <= m_run + 8.f)) {
            float mn  = fmaxf(m_run, rmax);
            float fac = __builtin_exp2f(m_run - mn);
            m_run = mn;
            l_run *= fac;
#pragma unroll
            for (int r = 0; r < 16; ++r) { o0[r] *= fac; o1[r] *= fac; }
        }
        float sum = 0.f;
#pragma unroll
        for (int r = 0; r < 32; ++r) { pv[r] = __builtin_exp2f(pv[r] - m_run); sum += pv[r]; }
        sum += __shfl_xor(sum, 32);
        l_run += sum;

        // ---- stage next V tile into LDS (writes to nxt buffer; no barrier needed)
        if (has_next) {
            char* VtN = (char*)Vt[nxt];
#pragma unroll
            for (int p = 0; p < 2; ++p)
#pragma unroll
                for (int e = 0; e < 8; ++e) {
                    int d = vd + p*32 + e;
                    *(bf16_t*)(VtN + ((d*128 + vkey*2) ^ ((d & 7) << 4))) = vvn[p][e];
                }
        }

        // ---- pack P to bf16, half-wave exchange, PV MFMAs
        const char* VtB = (const char*)Vt[cur];
#pragma unroll
        for (int kt = 0; kt < 2; ++kt) {
            u32 w[8];
#pragma unroll
            for (int i = 0; i < 8; ++i) w[i] = pk2(pv[kt*16 + 2*i], pv[kt*16 + 2*i + 1]);
#pragma unroll
            for (int c = 0; c < 2; ++c) {
                u32 z0 = hib ? w[4*c]     : w[4*c + 2];
                u32 z1 = hib ? w[4*c + 1] : w[4*c + 3];
                u32 sz0 = (u32)__shfl_xor((int)z0, 32);
                u32 sz1 = (u32)__shfl_xor((int)z1, 32);
                u32x4 fwv;
                fwv[0] = hib ? sz0 : w[4*c];
                fwv[1] = hib ? sz1 : w[4*c + 1];
                fwv[2] = hib ? w[4*c + 2] : sz0;
                fwv[3] = hib ? w[4*c + 3] : sz1;
                bf16x8 pfrag = __builtin_bit_cast(bf16x8, fwv);
                int colb = kt*64 + c*32 + hi*16;
                {
                    int row = lr5;
                    bf16x8 vf = *(const bf16x8*)(VtB + ((row*128 + colb) ^ ((row & 7) << 4)));
                    o0 = __builtin_amdgcn_mfma_f32_32x32x16_bf16(vf, pfrag, o0, 0, 0, 0);
                }
                {
                    int row = 32 + lr5;
                    bf16x8 vf = *(const bf16x8*)(VtB + ((row*128 + colb) ^ ((row & 7) << 4)));
                    o1 = __builtin_amdgcn_mfma_f32_32x32x16_bf16(vf, pfrag, o1, 0, 0, 0);
                }
            }
        }
        __syncthreads();
    }

    // ---- epilogue: O^T / l, transpose through LDS, coalesced global store
    float inv = 1.f / l_run;
    char* TrB = (char*)Ks;           // 16KB, reuse (all reads done: final barrier above)
    const int qloc = wave*32 + lr5;
#pragma unroll
    for (int mt = 0; mt < 2; ++mt)
#pragma unroll
        for (int r = 0; r < 16; ++r) {
            int d = mt*32 + (r & 3) + 8*(r >> 2) + 4*hi;
            float val = (mt ? o1[r] : o0[r]) * inv;
            *(bf16_t*)(TrB + (qloc*128 + ((d*2) ^ ((qloc & 7) << 4)))) = (bf16_t)val;
        }
    __syncthreads();
#pragma unroll
    for (int p = 0; p < 4; ++p) {
        int id = p*256 + tid;
        int row = id >> 3, g = id & 7;
        bf16x8 v8 = *(const bf16x8*)(TrB + (row*128 + ((g*16) ^ ((row & 7) << 4))));
        *(bf16x8*)&AO[base + (size_t)(q0 + row)*D_MODEL + g*8] = v8;
    }
}

extern "C" void kernel_launch(void* const* d_in, const int* in_sizes, int n_in,
                              void* d_out, int out_size, void* d_ws, size_t ws_size,
                              hipStream_t stream) {
    (void)in_sizes; (void)n_in; (void)out_size; (void)ws_size;
    const float* q    = (const float*)d_in[0];
    const float* k    = (const float*)d_in[1];
    const float* v    = (const float*)d_in[2];
    const int*   mask = (const int*)d_in[3];
    const float* wq_w = (const float*)d_in[4];
    const float* wq_b = (const float*)d_in[5];
    const float* wk_w = (const float*)d_in[6];
    const float* wk_b = (const float*)d_in[7];
    const float* wv_w = (const float*)d_in[8];
    const float* wv_b = (const float*)d_in[9];
    const float* wo_w = (const float*)d_in[10];
    const float* wo_b = (const float*)d_in[11];
    float* out = (float*)d_out;

    const size_t ACT = (size_t)MROWS * D_MODEL;
    const size_t WSZ = (size_t)D_MODEL * D_MODEL;
    bf16_t* Xb = (bf16_t*)d_ws;
    bf16_t* Qp = Xb + ACT;
    bf16_t* Kp = Qp + ACT;
    bf16_t* Vp = Kp + ACT;
    bf16_t* Wq = Vp + ACT;
    bf16_t* Wk = Wq + WSZ;
    bf16_t* Wv = Wk + WSZ;
    bf16_t* Wo = Wv + WSZ;
    bf16_t* AO = Xb;

    const int wn8 = (int)(WSZ/8), an8 = (int)(ACT/8);
    cvt_kernel<<<dim3(wn8/256), dim3(256), 0, stream>>>(wq_w, Wq, wn8);
    cvt_kernel<<<dim3(wn8/256), dim3(256), 0, stream>>>(wk_w, Wk, wn8);
    cvt_kernel<<<dim3(wn8/256), dim3(256), 0, stream>>>(wv_w, Wv, wn8);
    cvt_kernel<<<dim3(wn8/256), dim3(256), 0, stream>>>(wo_w, Wo, wn8);

    dim3 ggrid(MROWS/128, D_MODEL/128);
    cvt_kernel<<<dim3(an8/256), dim3(256), 0, stream>>>(q, Xb, an8);
    gemm_bt<1><<<ggrid, dim3(256), 0, stream>>>(Xb, Wq, wq_b, Qp, nullptr, MROWS, D_MODEL, D_MODEL);
    cvt_kernel<<<dim3(an8/256), dim3(256), 0, stream>>>(k, Xb, an8);
    gemm_bt<1><<<ggrid, dim3(256), 0, stream>>>(Xb, Wk, wk_b, Kp, nullptr, MROWS, D_MODEL, D_MODEL);
    cvt_kernel<<<dim3(an8/256), dim3(256), 0, stream>>>(v, Xb, an8);
    gemm_bt<1><<<ggrid, dim3(256), 0, stream>>>(Xb, Wv, wv_b, Vp, nullptr, MROWS, D_MODEL, D_MODEL);

    attn_kernel<<<dim3(SEQ/128, NHEAD, BATCH), dim3(256), 0, stream>>>(Qp, Kp, Vp, mask, AO);

    gemm_bt<0><<<ggrid, dim3(256), 0, stream>>>(AO, Wo, wo_b, nullptr, out, MROWS, D_MODEL, D_MODEL);
}

// Round 4
// 285.409 us; speedup vs baseline: 1.3089x; 1.0441x over previous
//
#include <hip/hip_runtime.h>
#include <hip/hip_bf16.h>
#include <stdint.h>

typedef __bf16 bf16_t;
typedef __bf16 bf16x8 __attribute__((ext_vector_type(8)));
typedef __bf16 bf16x2 __attribute__((ext_vector_type(2)));
typedef float  f32x4  __attribute__((ext_vector_type(4)));
typedef float  f32x16 __attribute__((ext_vector_type(16)));
typedef unsigned int u32;
typedef u32 u32x4 __attribute__((ext_vector_type(4)));

#define D_MODEL 1024
#define NHEAD   16
#define DEPTH   64
#define BATCH   4
#define SEQ     2048
#define MROWS   (BATCH*SEQ)

// 0.125 (1/sqrt(64)) * log2(e): softmax in exp2 domain
#define SC 0.18033688011112042f

__device__ __forceinline__ void gload16(const void* g, void* l) {
    __builtin_amdgcn_global_load_lds(
        (__attribute__((address_space(1))) void*)(uintptr_t)g,
        (__attribute__((address_space(3))) void*)l,
        16, 0, 0);
}

__device__ __forceinline__ u32 pk2(float a, float b) {
    bf16x2 t; t[0] = (bf16_t)a; t[1] = (bf16_t)b;
    return __builtin_bit_cast(u32, t);
}

// ---------------- f32 -> bf16 convert (16B/lane) ----------------
__global__ __launch_bounds__(256) void cvt_kernel(const float* __restrict__ src,
                                                  bf16_t* __restrict__ dst, int n8) {
    int i = blockIdx.x * 256 + threadIdx.x;
    if (i >= n8) return;
    const float4* s4 = (const float4*)src;
    float4 a = s4[2*(size_t)i], b = s4[2*(size_t)i + 1];
    bf16x8 o;
    o[0] = (bf16_t)a.x; o[1] = (bf16_t)a.y; o[2] = (bf16_t)a.z; o[3] = (bf16_t)a.w;
    o[4] = (bf16_t)b.x; o[5] = (bf16_t)b.y; o[6] = (bf16_t)b.z; o[7] = (bf16_t)b.w;
    *(bf16x8*)(dst + 8*(size_t)i) = o;
}

// ---------------- V transpose: Vp[b][s][h*64+d] -> Vt[b*16+h][d][s'] ----------------
// s' layout has bits 2,3 of (s&15) swapped, so attn P-fragments need NO lane exchange
// (MFMA k-permutation applied identically to A and B operands).
__global__ __launch_bounds__(256) void vtrans_kernel(const bf16_t* __restrict__ Vp,
                                                     bf16_t* __restrict__ Vt) {
    __shared__ bf16_t T[64][257];   // pad to 257 elems: spreads d-rows across banks
    const int bh = blockIdx.y;      // b*16+h
    const int b = bh >> 4, h = bh & 15;
    const int s0 = blockIdx.x * 256;
    const int tid = threadIdx.x;
#pragma unroll
    for (int p = 0; p < 8; ++p) {
        int id = p*256 + tid;
        int sl = id >> 3, dg = id & 7;
        bf16x8 v = *(const bf16x8*)&Vp[((size_t)b*SEQ + s0 + sl)*D_MODEL + h*DEPTH + dg*8];
#pragma unroll
        for (int e = 0; e < 8; ++e) T[dg*8 + e][sl] = v[e];
    }
    __syncthreads();
#pragma unroll
    for (int p = 0; p < 8; ++p) {
        int id = p*256 + tid;
        int d = id >> 5, sg = id & 31;
        bf16x8 o;
#pragma unroll
        for (int e = 0; e < 8; ++e) {
            int sp = sg*8 + e;                                   // target s' position
            int s  = (sp & ~12) | ((sp & 4) << 1) | ((sp & 8) >> 1); // swap bits 2,3
            o[e] = T[d][s];
        }
        *(bf16x8*)&Vt[((size_t)bh*DEPTH + d)*SEQ + s0 + sg*8] = o;
    }
}

// ---------------- GEMM: C[M,N] = A[M,K] * Bw[N,K]^T + bias ----------------
template<int OUT_BF16>
__global__ __launch_bounds__(256) void gemm_bt(const bf16_t* __restrict__ A,
                                               const bf16_t* __restrict__ Bw,
                                               const float* __restrict__ bias,
                                               bf16_t* __restrict__ Cb,
                                               float* __restrict__ Cf,
                                               int M, int N, int K) {
    __shared__ bf16_t As[128*64];
    __shared__ bf16_t Bs[128*64];
    const int tid  = threadIdx.x;
    const int wave = tid >> 6, lane = tid & 63;
    const int lr = lane & 15, lk = (lane >> 4) * 8;
    const int bm = blockIdx.x * 128, bn = blockIdx.y * 128;
    const int wr = (wave >> 1) * 64, wc = (wave & 1) * 64;

    f32x4 acc[4][4] = {};

    for (int kt = 0; kt < K; kt += 64) {
#pragma unroll
        for (int p = 0; p < 4; ++p) {
            int chunk = p*256 + tid;
            int r  = chunk >> 3;
            int cs = ((chunk & 7) ^ (r & 7)) * 8;
            gload16(A  + (size_t)(bm + r)*K + kt + cs, As + (size_t)(p*256 + wave*64)*8);
            gload16(Bw + (size_t)(bn + r)*K + kt + cs, Bs + (size_t)(p*256 + wave*64)*8);
        }
        __syncthreads();
        const char* AsB = (const char*)As;
        const char* BsB = (const char*)Bs;
#pragma unroll
        for (int ks = 0; ks < 2; ++ks) {
            int kb = (ks*32 + lk) * 2;
            bf16x8 af[4], bfv[4];
#pragma unroll
            for (int mi = 0; mi < 4; ++mi) {
                int row = wr + mi*16 + lr;
                af[mi] = *(const bf16x8*)(AsB + ((row*128 + kb) ^ ((row & 7) << 4)));
            }
#pragma unroll
            for (int ni = 0; ni < 4; ++ni) {
                int row = wc + ni*16 + lr;
                bfv[ni] = *(const bf16x8*)(BsB + ((row*128 + kb) ^ ((row & 7) << 4)));
            }
            __builtin_amdgcn_s_setprio(1);
#pragma unroll
            for (int mi = 0; mi < 4; ++mi)
#pragma unroll
                for (int ni = 0; ni < 4; ++ni)
                    acc[mi][ni] = __builtin_amdgcn_mfma_f32_16x16x32_bf16(
                        af[mi], bfv[ni], acc[mi][ni], 0, 0, 0);
            __builtin_amdgcn_s_setprio(0);
        }
        __syncthreads();
    }

#pragma unroll
    for (int ni = 0; ni < 4; ++ni) {
        int col = bn + wc + ni*16 + lr;
        float bv = bias[col];
#pragma unroll
        for (int mi = 0; mi < 4; ++mi) {
#pragma unroll
            for (int j = 0; j < 4; ++j) {
                int row = bm + wr + mi*16 + (lane >> 4)*4 + j;
                float vv = acc[mi][ni][j] + bv;
                if (OUT_BF16) Cb[(size_t)row*N + col] = (bf16_t)vv;
                else          Cf[(size_t)row*N + col] = vv;
            }
        }
    }
}

// ---------------- Flash attention ----------------
// 128 q/block, 4 waves x 32 q. 64-key tiles, double-buffered K,V^T in LDS, both
// staged via global_load_lds (V pre-transposed + key-bit-swapped in global memory).
// S^T = mfma(K, Q^T): lane owns one q-row; softmax in-register; P-fragments are a
// direct pack of consecutive pv[] (no lane exchange). O^T = mfma(V^T, P^T).
__global__ __launch_bounds__(256) void attn_kernel(const bf16_t* __restrict__ Qp,
                                                   const bf16_t* __restrict__ Kp,
                                                   const bf16_t* __restrict__ Vt,
                                                   const int* __restrict__ mask,
                                                   bf16_t* __restrict__ AO) {
    __shared__ bf16_t Ks[2][64*64];   // [key][d], XOR-swizzled via pre-swizzled src
    __shared__ bf16_t Vs[2][64*64];   // [d][key-position], XOR-swizzled
    __shared__ float  mb[2][64];      // additive mask bias (0 or -1e30)

    const int tid  = threadIdx.x;
    const int wave = tid >> 6, lane = tid & 63;
    const int lr5 = lane & 31;
    const int hi  = lane >> 5;
    const int b = blockIdx.z, h = blockIdx.y, q0 = blockIdx.x * 128;
    const int qw = q0 + wave*32;
    const size_t base  = (size_t)b * SEQ * D_MODEL + (size_t)h * DEPTH;
    const size_t vbase = ((size_t)(b*NHEAD + h)) * DEPTH * SEQ;

    // Q fragments (B-operand: lane holds Q[q = qw+lr5][d = dc*16 + hi*8 + e])
    bf16x8 qf[4];
#pragma unroll
    for (int dc = 0; dc < 4; ++dc)
        qf[dc] = *(const bf16x8*)&Qp[base + (size_t)(qw + lr5)*D_MODEL + dc*16 + hi*8];

    f32x16 o0 = {}, o1 = {};          // O^T accumulators: d 0..31 / 32..63, col=q
    float m_run = -1e30f, l_run = 0.f;

    // ---- prologue: stage tile 0
    {
#pragma unroll
        for (int p = 0; p < 2; ++p) {
            int chunk = p*256 + tid; int r = chunk >> 3;
            int cs = ((chunk & 7) ^ (r & 7)) * 8;
            gload16(Kp + base + (size_t)r*D_MODEL + cs, (bf16_t*)Ks[0] + (size_t)chunk*8);
            gload16(Vt + vbase + (size_t)r*SEQ + cs,   (bf16_t*)Vs[0] + (size_t)chunk*8);
        }
        if (tid < 64) mb[0][tid] = (mask[(size_t)b*SEQ + tid] == 0) ? -1e30f : 0.f;
    }
    __syncthreads();

    for (int t = 0; t < SEQ/64; ++t) {
        const int cur = t & 1, nxt = cur ^ 1;
        if (t + 1 < SEQ/64) {
#pragma unroll
            for (int p = 0; p < 2; ++p) {
                int chunk = p*256 + tid; int r = chunk >> 3;
                int cs = ((chunk & 7) ^ (r & 7)) * 8;
                gload16(Kp + base + (size_t)((t+1)*64 + r)*D_MODEL + cs,
                        (bf16_t*)Ks[nxt] + (size_t)chunk*8);
                gload16(Vt + vbase + (size_t)r*SEQ + (t+1)*64 + cs,
                        (bf16_t*)Vs[nxt] + (size_t)chunk*8);
            }
            if (tid < 64) mb[nxt][tid] = (mask[(size_t)b*SEQ + (t+1)*64 + tid] == 0) ? -1e30f : 0.f;
        }

        // ---- QK^T: S^T[key][q]
        const char* KsB = (const char*)Ks[cur];
        f32x16 s0 = {}, s1 = {};
#pragma unroll
        for (int dc = 0; dc < 4; ++dc) {
            int colb = dc*32 + hi*16;
            int row0 = lr5, row1 = 32 + lr5;
            bf16x8 kf0 = *(const bf16x8*)(KsB + ((row0*128 + colb) ^ ((row0 & 7) << 4)));
            bf16x8 kf1 = *(const bf16x8*)(KsB + ((row1*128 + colb) ^ ((row1 & 7) << 4)));
            __builtin_amdgcn_s_setprio(1);
            s0 = __builtin_amdgcn_mfma_f32_32x32x16_bf16(kf0, qf[dc], s0, 0, 0, 0);
            s1 = __builtin_amdgcn_mfma_f32_32x32x16_bf16(kf1, qf[dc], s1, 0, 0, 0);
            __builtin_amdgcn_s_setprio(0);
        }

        // ---- mask bias (key-local for pv[r] = (r&3) + 8*(r>>2) + 4*hi)
        const float* mbp = mb[cur];
        f32x4 mv[2][4];
#pragma unroll
        for (int kt = 0; kt < 2; ++kt)
#pragma unroll
            for (int g = 0; g < 4; ++g)
                mv[kt][g] = *(const f32x4*)&mbp[kt*32 + g*8 + hi*4];

        float pv[32];
#pragma unroll
        for (int r = 0; r < 16; ++r) {
            pv[r]      = s0[r]*SC + mv[0][r>>2][r&3];
            pv[16 + r] = s1[r]*SC + mv[1][r>>2][r&3];
        }

        // ---- online softmax (exp2 domain); cross-half via shfl_xor(32)
        float rmax = fmaxf(pv[0], pv[1]);
#pragma unroll
        for (int r = 2; r < 32; r += 2) rmax = fmaxf(fmaxf(pv[r], pv[r+1]), rmax);
        rmax = fmaxf(rmax, __shfl_xor(rmax, 32));

        if (!__all(rmax <= m_run + 8.f)) {
            float mn  = fmaxf(m_run, rmax);
            float fac = __builtin_exp2f(m_run - mn);
            m_run = mn;
            l_run *= fac;
#pragma unroll
            for (int r = 0; r < 16; ++r) { o0[r] *= fac; o1[r] *= fac; }
        }
        float sum = 0.f;
#pragma unroll
        for (int r = 0; r < 32; ++r) { pv[r] = __builtin_exp2f(pv[r] - m_run); sum += pv[r]; }
        sum += __shfl_xor(sum, 32);
        l_run += sum;

        // ---- PV: P-fragment = direct pack of 8 consecutive pv (key-bit-swap layout).
        // Build as u32x4 VALUE + bit_cast (NO pointer casts: strict-aliasing-safe).
        const char* VsB = (const char*)Vs[cur];
#pragma unroll
        for (int kt = 0; kt < 2; ++kt) {
#pragma unroll
            for (int c = 0; c < 2; ++c) {
                u32x4 fwv;
#pragma unroll
                for (int i = 0; i < 4; ++i)
                    fwv[i] = pk2(pv[kt*16 + c*8 + 2*i], pv[kt*16 + c*8 + 2*i + 1]);
                bf16x8 pfrag = __builtin_bit_cast(bf16x8, fwv);
                int colb = kt*64 + c*32 + hi*16;
                int row0 = lr5, row1 = 32 + lr5;
                bf16x8 vf0 = *(const bf16x8*)(VsB + ((row0*128 + colb) ^ ((row0 & 7) << 4)));
                bf16x8 vf1 = *(const bf16x8*)(VsB + ((row1*128 + colb) ^ ((row1 & 7) << 4)));
                __builtin_amdgcn_s_setprio(1);
                o0 = __builtin_amdgcn_mfma_f32_32x32x16_bf16(vf0, pfrag, o0, 0, 0, 0);
                o1 = __builtin_amdgcn_mfma_f32_32x32x16_bf16(vf1, pfrag, o1, 0, 0, 0);
                __builtin_amdgcn_s_setprio(0);
            }
        }
        __syncthreads();
    }

    // ---- epilogue: O^T / l, transpose through LDS, coalesced global store
    float inv = 1.f / l_run;
    char* TrB = (char*)Ks;            // reuse (last barrier protects)
    const int qloc = wave*32 + lr5;
#pragma unroll
    for (int mt = 0; mt < 2; ++mt)
#pragma unroll
        for (int r = 0; r < 16; ++r) {
            int d = mt*32 + (r & 3) + 8*(r >> 2) + 4*hi;
            float val = (mt ? o1[r] : o0[r]) * inv;
            *(bf16_t*)(TrB + (qloc*128 + ((d*2) ^ ((qloc & 7) << 4)))) = (bf16_t)val;
        }
    __syncthreads();
#pragma unroll
    for (int p = 0; p < 4; ++p) {
        int id = p*256 + tid;
        int row = id >> 3, g = id & 7;
        bf16x8 v8 = *(const bf16x8*)(TrB + (row*128 + ((g*16) ^ ((row & 7) << 4))));
        *(bf16x8*)&AO[base + (size_t)(q0 + row)*D_MODEL + g*8] = v8;
    }
}

extern "C" void kernel_launch(void* const* d_in, const int* in_sizes, int n_in,
                              void* d_out, int out_size, void* d_ws, size_t ws_size,
                              hipStream_t stream) {
    (void)in_sizes; (void)n_in; (void)out_size; (void)ws_size;
    const float* q    = (const float*)d_in[0];
    const float* k    = (const float*)d_in[1];
    const float* v    = (const float*)d_in[2];
    const int*   mask = (const int*)d_in[3];
    const float* wq_w = (const float*)d_in[4];
    const float* wq_b = (const float*)d_in[5];
    const float* wk_w = (const float*)d_in[6];
    const float* wk_b = (const float*)d_in[7];
    const float* wv_w = (const float*)d_in[8];
    const float* wv_b = (const float*)d_in[9];
    const float* wo_w = (const float*)d_in[10];
    const float* wo_b = (const float*)d_in[11];
    float* out = (float*)d_out;

    const size_t ACT = (size_t)MROWS * D_MODEL;
    const size_t WSZ = (size_t)D_MODEL * D_MODEL;
    bf16_t* Xb = (bf16_t*)d_ws;       // cvt staging -> later Vt
    bf16_t* Qp = Xb + ACT;
    bf16_t* Kp = Qp + ACT;
    bf16_t* Vp = Kp + ACT;            // V projected -> later attn output AO
    bf16_t* Wq = Vp + ACT;
    bf16_t* Wk = Wq + WSZ;
    bf16_t* Wv = Wk + WSZ;
    bf16_t* Wo = Wv + WSZ;
    bf16_t* Vt = Xb;
    bf16_t* AO = Vp;

    const int wn8 = (int)(WSZ/8), an8 = (int)(ACT/8);
    cvt_kernel<<<dim3(wn8/256), dim3(256), 0, stream>>>(wq_w, Wq, wn8);
    cvt_kernel<<<dim3(wn8/256), dim3(256), 0, stream>>>(wk_w, Wk, wn8);
    cvt_kernel<<<dim3(wn8/256), dim3(256), 0, stream>>>(wv_w, Wv, wn8);
    cvt_kernel<<<dim3(wn8/256), dim3(256), 0, stream>>>(wo_w, Wo, wn8);

    dim3 ggrid(MROWS/128, D_MODEL/128);
    cvt_kernel<<<dim3(an8/256), dim3(256), 0, stream>>>(q, Xb, an8);
    gemm_bt<1><<<ggrid, dim3(256), 0, stream>>>(Xb, Wq, wq_b, Qp, nullptr, MROWS, D_MODEL, D_MODEL);
    cvt_kernel<<<dim3(an8/256), dim3(256), 0, stream>>>(k, Xb, an8);
    gemm_bt<1><<<ggrid, dim3(256), 0, stream>>>(Xb, Wk, wk_b, Kp, nullptr, MROWS, D_MODEL, D_MODEL);
    cvt_kernel<<<dim3(an8/256), dim3(256), 0, stream>>>(v, Xb, an8);
    gemm_bt<1><<<ggrid, dim3(256), 0, stream>>>(Xb, Wv, wv_b, Vp, nullptr, MROWS, D_MODEL, D_MODEL);

    vtrans_kernel<<<dim3(SEQ/256, NHEAD*BATCH), dim3(256), 0, stream>>>(Vp, Vt);

    attn_kernel<<<dim3(SEQ/128, NHEAD, BATCH), dim3(256), 0, stream>>>(Qp, Kp, Vt, mask, AO);

    gemm_bt<0><<<ggrid, dim3(256), 0, stream>>>(AO, Wo, wo_b, nullptr, out, MROWS, D_MODEL, D_MODEL);
}